// Round 4
// baseline (124.661 us; speedup 1.0000x reference)
//
#include <hip/hip_runtime.h>

#define N_NODES 8000
#define E_EDGES 128000
#define NUM_BASES 50
#define R2 400
#define CPR 4      // chunks per relation in edge kernel
#define RT 16      // relation tile in relw

static __device__ __forceinline__ float bf2f(unsigned short u) {
    return __uint_as_float(((unsigned int)u) << 16);
}
static __device__ __forceinline__ unsigned short f2bf(float f) {
    unsigned int u = __float_as_uint(f);
    u += 0x7fffu + ((u >> 16) & 1u);   // round-to-nearest-even
    return (unsigned short)(u >> 16);
}
static __device__ __forceinline__ float bcast(float v, int lane) {
    return __uint_as_float(__builtin_amdgcn_readlane(__float_as_uint(v), lane));
}

// ---------------------------------------------------------------------------
// k_pre: blocks [0,100)   -> rel_weight (bf16) = w_comp @ weight (tiled)
//        blocks [100,600) -> etype histogram (64B-padded) + dst histogram
// ---------------------------------------------------------------------------
__global__ __launch_bounds__(256) void k_pre(const float* __restrict__ w_comp,
                                             const float* __restrict__ weight,
                                             unsigned short* __restrict__ relWh,
                                             const int* __restrict__ dst,
                                             const int* __restrict__ etype,
                                             int* __restrict__ cnt16,
                                             int* __restrict__ dcnt) {
    const int blk = blockIdx.x;
    const int t = threadIdx.x;
    if (blk < 100) {
        const int rt = blk >> 2;                 // relation tile [0,25)
        const int pb = blk & 3;                  // position block
        const int r0 = rt * RT;
        const int p = pb * 256 + t;              // float4 index [0,1024)
        const float4* w4 = (const float4*)weight;
        float4 acc[RT];
#pragma unroll
        for (int rr = 0; rr < RT; ++rr) acc[rr] = make_float4(0.f, 0.f, 0.f, 0.f);
        for (int b = 0; b < NUM_BASES; ++b) {
            const float4 w = w4[b * 1024 + p];
#pragma unroll
            for (int rr = 0; rr < RT; ++rr) {
                const float c = w_comp[(r0 + rr) * NUM_BASES + b];
                acc[rr].x = fmaf(c, w.x, acc[rr].x);
                acc[rr].y = fmaf(c, w.y, acc[rr].y);
                acc[rr].z = fmaf(c, w.z, acc[rr].z);
                acc[rr].w = fmaf(c, w.w, acc[rr].w);
            }
        }
        ushort4* outh = (ushort4*)relWh;
#pragma unroll
        for (int rr = 0; rr < RT; ++rr) {
            ushort4 v;
            v.x = f2bf(acc[rr].x); v.y = f2bf(acc[rr].y);
            v.z = f2bf(acc[rr].z); v.w = f2bf(acc[rr].w);
            outh[(r0 + rr) * 1024 + p] = v;
        }
    } else {
        const int e = (blk - 100) * 256 + t;
        if (e >= E_EDGES) return;
        atomicAdd(&cnt16[etype[e] * 16], 1);     // one 64B line per counter
        atomicAdd(&dcnt[dst[e]], 1);
    }
}

// ---------------------------------------------------------------------------
// k_scan: block 0 -> exclusive scan of 400 etype bins -> off[401]
//         block 1 -> exclusive scan of 8000 dst bins  -> doff[8001]
// ---------------------------------------------------------------------------
__global__ __launch_bounds__(1024) void k_scan(const int* __restrict__ cnt16,
                                               const int* __restrict__ dcnt,
                                               int* __restrict__ off,
                                               int* __restrict__ doff) {
    __shared__ int s[1024];
    const int t = threadIdx.x;
    if (blockIdx.x == 0) {
        s[t] = (t < R2) ? cnt16[t * 16] : 0;
        __syncthreads();
        for (int d = 1; d < 1024; d <<= 1) {
            const int v = (t >= d) ? s[t - d] : 0;
            __syncthreads();
            s[t] += v;
            __syncthreads();
        }
        if (t == 0) off[0] = 0;
        if (t < R2) off[t + 1] = s[t];
    } else {
        const int base = t * 8;
        int loc[8];
        int run = 0;
#pragma unroll
        for (int q = 0; q < 8; ++q) {
            const int v = (base + q < N_NODES) ? dcnt[base + q] : 0;
            loc[q] = run;
            run += v;
        }
        s[t] = run;
        __syncthreads();
        for (int d = 1; d < 1024; d <<= 1) {
            const int v = (t >= d) ? s[t - d] : 0;
            __syncthreads();
            s[t] += v;
            __syncthreads();
        }
        const int ex = s[t] - run;
#pragma unroll
        for (int q = 0; q < 8; ++q)
            if (base + q < N_NODES) doff[base + q] = ex + loc[q];
        if (t == 1023) doff[N_NODES] = s[1023];
    }
}

// ---------------------------------------------------------------------------
// k_scatter: counting-sort by etype (ssrc/sdst at rpos) AND build dst-sorted
// permutation dperm[dst-order] = rpos (relation-sorted msg row index).
// ---------------------------------------------------------------------------
__global__ __launch_bounds__(256) void k_scatter(const int* __restrict__ src,
                                                 const int* __restrict__ dst,
                                                 const int* __restrict__ etype,
                                                 const int* __restrict__ off,
                                                 const int* __restrict__ doff,
                                                 int* __restrict__ cursor16,
                                                 int* __restrict__ dcursor,
                                                 int* __restrict__ ssrc,
                                                 int* __restrict__ sdst,
                                                 int* __restrict__ dperm) {
    const int e = blockIdx.x * 256 + threadIdx.x;
    if (e >= E_EDGES) return;
    const int r = etype[e];
    const int rpos = off[r] + atomicAdd(&cursor16[r * 16], 1);
    ssrc[rpos] = src[e];
    sdst[rpos] = dst[e];
    const int d = dst[e];
    const int dpos = doff[d] + atomicAdd(&dcursor[d], 1);
    dperm[dpos] = rpos;
}

// ---------------------------------------------------------------------------
// k_edge (primary): relation-binned edge messages -> plain bf16 stores.
// XCD-banded; W[r] column in registers; 2-edge ILP scalar-load pipeline.
// ---------------------------------------------------------------------------
__global__ __launch_bounds__(256) void k_edge(const float* __restrict__ feat,
                                              const unsigned short* __restrict__ relWh,
                                              const int* __restrict__ ssrc,
                                              const int* __restrict__ off,
                                              unsigned short* __restrict__ msg) {
    const int xcd = blockIdx.x & 7;
    const int j = blockIdx.x >> 3;           // [0,200)
    const int r = xcd * 50 + (j >> 2);       // CPR=4
    const int chunk = j & 3;
    const int lane = threadIdx.x & 63;
    const int wv = threadIdx.x >> 6;
    const int beg = off[r];
    const int cnt = off[r + 1] - beg;
    const int cbeg = beg + (cnt * chunk) / CPR;
    const int cend = beg + (cnt * (chunk + 1)) / CPR;

    const unsigned short* __restrict__ Wh = relWh + r * 4096;
    float w[64];
#pragma unroll
    for (int i = 0; i < 64; ++i) w[i] = bf2f(Wh[i * 64 + lane]);

    int idx = cbeg + wv;
    for (; idx + 4 < cend; idx += 8) {
        const int iB = idx + 4;
        const int sA = __builtin_amdgcn_readfirstlane(ssrc[idx]);
        const int sB = __builtin_amdgcn_readfirstlane(ssrc[iB]);
        const float* __restrict__ fA = feat + sA * 64;   // uniform -> s_load
        const float* __restrict__ fB = feat + sB * 64;
        float a0 = 0.f, a1 = 0.f, a2 = 0.f, a3 = 0.f;
        float b0 = 0.f, b1 = 0.f, b2 = 0.f, b3 = 0.f;
#pragma unroll
        for (int i = 0; i < 64; i += 4) {
            a0 = fmaf(fA[i    ], w[i    ], a0);  b0 = fmaf(fB[i    ], w[i    ], b0);
            a1 = fmaf(fA[i + 1], w[i + 1], a1);  b1 = fmaf(fB[i + 1], w[i + 1], b1);
            a2 = fmaf(fA[i + 2], w[i + 2], a2);  b2 = fmaf(fB[i + 2], w[i + 2], b2);
            a3 = fmaf(fA[i + 3], w[i + 3], a3);  b3 = fmaf(fB[i + 3], w[i + 3], b3);
        }
        msg[idx * 64 + lane] = f2bf((a0 + a1) + (a2 + a3));
        msg[iB * 64 + lane] = f2bf((b0 + b1) + (b2 + b3));
    }
    for (; idx < cend; idx += 4) {
        const int s = __builtin_amdgcn_readfirstlane(ssrc[idx]);
        const float* __restrict__ frow = feat + s * 64;
        float a0 = 0.f, a1 = 0.f, a2 = 0.f, a3 = 0.f;
#pragma unroll
        for (int i = 0; i < 64; i += 4) {
            a0 = fmaf(frow[i    ], w[i    ], a0);
            a1 = fmaf(frow[i + 1], w[i + 1], a1);
            a2 = fmaf(frow[i + 2], w[i + 2], a2);
            a3 = fmaf(frow[i + 3], w[i + 3], a3);
        }
        msg[idx * 64 + lane] = f2bf((a0 + a1) + (a2 + a3));
    }
}

// ---------------------------------------------------------------------------
// k_edge_at (fallback): round-3 atomic edge kernel, bf16 weights.
// ---------------------------------------------------------------------------
__global__ __launch_bounds__(256) void k_edge_at(const float* __restrict__ feat,
                                                 const unsigned short* __restrict__ relWh,
                                                 const int* __restrict__ ssrc,
                                                 const int* __restrict__ sdst,
                                                 const int* __restrict__ off,
                                                 float* __restrict__ nei_sum) {
    const int xcd = blockIdx.x & 7;
    const int j = blockIdx.x >> 3;
    const int r = xcd * 50 + (j >> 2);
    const int chunk = j & 3;
    const int lane = threadIdx.x & 63;
    const int wv = threadIdx.x >> 6;
    const int beg = off[r];
    const int cnt = off[r + 1] - beg;
    const int cbeg = beg + (cnt * chunk) / CPR;
    const int cend = beg + (cnt * (chunk + 1)) / CPR;

    const unsigned short* __restrict__ Wh = relWh + r * 4096;
    float w[64];
#pragma unroll
    for (int i = 0; i < 64; ++i) w[i] = bf2f(Wh[i * 64 + lane]);

    for (int idx = cbeg + wv; idx < cend; idx += 4) {
        const int s = __builtin_amdgcn_readfirstlane(ssrc[idx]);
        const int d = __builtin_amdgcn_readfirstlane(sdst[idx]);
        const float* __restrict__ frow = feat + s * 64;
        float a0 = 0.f, a1 = 0.f, a2 = 0.f, a3 = 0.f;
#pragma unroll
        for (int i = 0; i < 64; i += 4) {
            a0 = fmaf(frow[i    ], w[i    ], a0);
            a1 = fmaf(frow[i + 1], w[i + 1], a1);
            a2 = fmaf(frow[i + 2], w[i + 2], a2);
            a3 = fmaf(frow[i + 3], w[i + 3], a3);
        }
        atomicAdd(&nei_sum[d * 64 + lane], (a0 + a1) + (a2 + a3));
    }
}

// ---------------------------------------------------------------------------
// k_post (primary): blocks [0,500)  -> node epilogue via dperm gather-sum
//                   blocks [500,600) -> rel_emb @ W_R^T + b
// ---------------------------------------------------------------------------
__global__ __launch_bounds__(256) void k_post(const float* __restrict__ feat,
                                              const float* __restrict__ slw,
                                              const int* __restrict__ doff,
                                              const int* __restrict__ dperm,
                                              const unsigned short* __restrict__ msg,
                                              const float* __restrict__ rel_emb,
                                              const float* __restrict__ Wr,
                                              const float* __restrict__ br,
                                              float* __restrict__ out) {
    __shared__ float s_w[4096];
    const int blk = blockIdx.x;
    const int t = threadIdx.x;
    const int lane = t & 63;
    const int wv = t >> 6;
    if (blk < 500) {
#pragma unroll
        for (int k = 0; k < 16; ++k) s_w[k * 256 + t] = slw[k * 256 + t];
        __syncthreads();
#pragma unroll
        for (int q = 0; q < 4; ++q) {
            const int n = blk * 16 + wv * 4 + q;
            const int b0 = doff[n];
            const int b1 = doff[n + 1];
            const float* __restrict__ frow = feat + n * 64;   // uniform -> s_load
            const float fa = frow[lane];
            float acc = 0.f;
#pragma unroll
            for (int i = 0; i < 64; ++i)
                acc = fmaf(frow[i], s_w[i * 64 + lane], acc);  // 2-way alias: free
            float sm = 0.f;
            int jj = b0;
            for (; jj + 1 < b1; jj += 2) {
                const int r0 = dperm[jj];
                const int r1 = dperm[jj + 1];
                sm += bf2f(msg[r0 * 64 + lane]) + bf2f(msg[r1 * 64 + lane]);
            }
            if (jj < b1) sm += bf2f(msg[dperm[jj] * 64 + lane]);
            const float inv = 1.0f / fmaxf((float)(b1 - b0), 1.0f);
            out[n * 128 + lane] = fa;
            out[n * 128 + 64 + lane] = fmaf(sm, inv, acc);
        }
    } else {
        // s_w[k*64+j] = Wr[j*64+k]
#pragma unroll
        for (int k = 0; k < 16; ++k) {
            const int idx = k * 256 + t;
            s_w[(idx & 63) * 64 + (idx >> 6)] = Wr[idx];
        }
        __syncthreads();
        const int r = (blk - 500) * 4 + wv;
        const float re = rel_emb[r * 64 + lane];
        float acc = br[lane];
#pragma unroll
        for (int k = 0; k < 64; ++k)
            acc = fmaf(bcast(re, k), s_w[k * 64 + lane], acc);
        out[N_NODES * 128 + r * 64 + lane] = acc;
    }
}

// ---------------------------------------------------------------------------
// k_post_at (fallback): reads nei_sum + dcnt (degree from histogram)
// ---------------------------------------------------------------------------
__global__ __launch_bounds__(256) void k_post_at(const float* __restrict__ feat,
                                                 const float* __restrict__ slw,
                                                 const float* __restrict__ nei_sum,
                                                 const int* __restrict__ dcnt,
                                                 const float* __restrict__ rel_emb,
                                                 const float* __restrict__ Wr,
                                                 const float* __restrict__ br,
                                                 float* __restrict__ out) {
    __shared__ float s_w[4096];
    const int blk = blockIdx.x;
    const int t = threadIdx.x;
    const int lane = t & 63;
    const int wv = t >> 6;
    if (blk < 500) {
#pragma unroll
        for (int k = 0; k < 16; ++k) s_w[k * 256 + t] = slw[k * 256 + t];
        __syncthreads();
#pragma unroll
        for (int q = 0; q < 4; ++q) {
            const int n = blk * 16 + wv * 4 + q;
            const float* __restrict__ frow = feat + n * 64;
            const float fa = frow[lane];
            float acc = 0.f;
#pragma unroll
            for (int i = 0; i < 64; ++i)
                acc = fmaf(frow[i], s_w[i * 64 + lane], acc);
            const float inv = 1.0f / fmaxf((float)dcnt[n], 1.0f);
            out[n * 128 + lane] = fa;
            out[n * 128 + 64 + lane] = fmaf(nei_sum[n * 64 + lane], inv, acc);
        }
    } else {
#pragma unroll
        for (int k = 0; k < 16; ++k) {
            const int idx = k * 256 + t;
            s_w[(idx & 63) * 64 + (idx >> 6)] = Wr[idx];
        }
        __syncthreads();
        const int r = (blk - 500) * 4 + wv;
        const float re = rel_emb[r * 64 + lane];
        float acc = br[lane];
#pragma unroll
        for (int k = 0; k < 64; ++k)
            acc = fmaf(bcast(re, k), s_w[k * 64 + lane], acc);
        out[N_NODES * 128 + r * 64 + lane] = acc;
    }
}

// ---------------------------------------------------------------------------
extern "C" void kernel_launch(void* const* d_in, const int* in_sizes, int n_in,
                              void* d_out, int out_size, void* d_ws, size_t ws_size,
                              hipStream_t stream) {
    const float* feat    = (const float*)d_in[0];   // [8000,64]
    const float* rel_emb = (const float*)d_in[1];   // [400,64]
    const float* weight  = (const float*)d_in[2];   // [50,64,64]
    const float* w_comp  = (const float*)d_in[3];   // [400,50]
    const float* slw     = (const float*)d_in[4];   // [64,64]
    const float* Wr      = (const float*)d_in[5];   // [64,64]
    const float* br      = (const float*)d_in[6];   // [64]
    const int*   src     = (const int*)d_in[7];     // [128000]
    const int*   dst     = (const int*)d_in[8];     // [128000]
    const int*   etype   = (const int*)d_in[9];     // [128000]
    float* out = (float*)d_out;
    char* ws = (char*)d_ws;

    if (ws_size >= 21345728) {
        // ---- primary layout (no atomics on the message path) ----
        unsigned short* relWh = (unsigned short*)(ws);            // 3,276,800
        unsigned short* msg   = (unsigned short*)(ws + 3276800);  // 16,384,000
        int* ssrc     = (int*)(ws + 19660800);                    //   512,000
        int* sdst     = (int*)(ws + 20172800);                    //   512,000
        int* dperm    = (int*)(ws + 20684800);                    //   512,000
        int* off      = (int*)(ws + 21196800);                    //     1,664
        int* doff     = (int*)(ws + 21198464);                    //    32,064
        int* cnt16    = (int*)(ws + 21230528);                    //    25,600
        int* cursor16 = (int*)(ws + 21256128);                    //    25,600
        int* dcnt     = (int*)(ws + 21281728);                    //    32,000
        int* dcursor  = (int*)(ws + 21313728);                    //    32,000

        hipMemsetAsync(cnt16, 0, 115200, stream);   // cnt16..dcursor contiguous
        k_pre<<<600, 256, 0, stream>>>(w_comp, weight, relWh, dst, etype,
                                       cnt16, dcnt);
        k_scan<<<2, 1024, 0, stream>>>(cnt16, dcnt, off, doff);
        k_scatter<<<500, 256, 0, stream>>>(src, dst, etype, off, doff,
                                           cursor16, dcursor, ssrc, sdst, dperm);
        k_edge<<<R2 * CPR, 256, 0, stream>>>(feat, relWh, ssrc, off, msg);
        k_post<<<600, 256, 0, stream>>>(feat, slw, doff, dperm, msg,
                                        rel_emb, Wr, br, out);
    } else {
        // ---- compact fallback (round-3 atomic pipeline, bf16 weights) ----
        unsigned short* relWh = (unsigned short*)(ws);            // 3,276,800
        int* ssrc     = (int*)(ws + 3276800);                     //   512,000
        int* sdst     = (int*)(ws + 3788800);                     //   512,000
        int* dperm    = (int*)(ws + 4300800);                     //   512,000
        int* off      = (int*)(ws + 4812800);                     //     1,664
        int* doff     = (int*)(ws + 4814464);                     //    32,064
        float* nei    = (float*)(ws + 4846528);                   // 2,048,000
        int* cnt16    = (int*)(ws + 6894528);                     //    25,600
        int* cursor16 = (int*)(ws + 6920128);                     //    25,600
        int* dcnt     = (int*)(ws + 6945728);                     //    32,000
        int* dcursor  = (int*)(ws + 6977728);                     //    32,000

        hipMemsetAsync(nei, 0, 2163200, stream);    // nei..dcursor contiguous
        k_pre<<<600, 256, 0, stream>>>(w_comp, weight, relWh, dst, etype,
                                       cnt16, dcnt);
        k_scan<<<2, 1024, 0, stream>>>(cnt16, dcnt, off, doff);
        k_scatter<<<500, 256, 0, stream>>>(src, dst, etype, off, doff,
                                           cursor16, dcursor, ssrc, sdst, dperm);
        k_edge_at<<<R2 * CPR, 256, 0, stream>>>(feat, relWh, ssrc, sdst, off, nei);
        k_post_at<<<600, 256, 0, stream>>>(feat, slw, nei, dcnt,
                                           rel_emb, Wr, br, out);
    }
}

// Round 5
// 119.451 us; speedup vs baseline: 1.0436x; 1.0436x over previous
//
#include <hip/hip_runtime.h>

#define N_NODES 8000
#define E_EDGES 128000
#define NUM_BASES 50
#define R2 400
#define CPR 4      // chunks per relation in edge kernel
#define RT 16      // relation tile in relw

static __device__ __forceinline__ float bf2f(unsigned short u) {
    return __uint_as_float(((unsigned int)u) << 16);
}
static __device__ __forceinline__ unsigned short f2bf(float f) {
    unsigned int u = __float_as_uint(f);
    u += 0x7fffu + ((u >> 16) & 1u);   // round-to-nearest-even
    return (unsigned short)(u >> 16);
}
static __device__ __forceinline__ float bcast(float v, int lane) {
    return __uint_as_float(__builtin_amdgcn_readlane(__float_as_uint(v), lane));
}

// ---------------------------------------------------------------------------
// k_pre: blocks [0,100)   -> rel_weight (bf16) = w_comp @ weight (tiled)
//        blocks [100,600) -> etype histogram (64B-padded) + dst histogram
// ---------------------------------------------------------------------------
__global__ __launch_bounds__(256) void k_pre(const float* __restrict__ w_comp,
                                             const float* __restrict__ weight,
                                             unsigned short* __restrict__ relWh,
                                             const int* __restrict__ dst,
                                             const int* __restrict__ etype,
                                             int* __restrict__ cnt16,
                                             int* __restrict__ dcnt) {
    const int blk = blockIdx.x;
    const int t = threadIdx.x;
    if (blk < 100) {
        const int rt = blk >> 2;                 // relation tile [0,25)
        const int pb = blk & 3;                  // position block
        const int r0 = rt * RT;
        const int p = pb * 256 + t;              // float4 index [0,1024)
        const float4* w4 = (const float4*)weight;
        float4 acc[RT];
#pragma unroll
        for (int rr = 0; rr < RT; ++rr) acc[rr] = make_float4(0.f, 0.f, 0.f, 0.f);
        for (int b = 0; b < NUM_BASES; ++b) {
            const float4 w = w4[b * 1024 + p];
#pragma unroll
            for (int rr = 0; rr < RT; ++rr) {
                const float c = w_comp[(r0 + rr) * NUM_BASES + b];
                acc[rr].x = fmaf(c, w.x, acc[rr].x);
                acc[rr].y = fmaf(c, w.y, acc[rr].y);
                acc[rr].z = fmaf(c, w.z, acc[rr].z);
                acc[rr].w = fmaf(c, w.w, acc[rr].w);
            }
        }
        ushort4* outh = (ushort4*)relWh;
#pragma unroll
        for (int rr = 0; rr < RT; ++rr) {
            ushort4 v;
            v.x = f2bf(acc[rr].x); v.y = f2bf(acc[rr].y);
            v.z = f2bf(acc[rr].z); v.w = f2bf(acc[rr].w);
            outh[(r0 + rr) * 1024 + p] = v;
        }
    } else {
        const int e = (blk - 100) * 256 + t;
        if (e >= E_EDGES) return;
        atomicAdd(&cnt16[etype[e] * 16], 1);     // one 64B line per counter
        atomicAdd(&dcnt[dst[e]], 1);
    }
}

// ---------------------------------------------------------------------------
// k_scan: block 0 -> scan 400 etype bins -> off[401], init cursor16 = off
//         block 1 -> scan 8000 dst bins  -> doff[8001], init dcursor = doff
// ---------------------------------------------------------------------------
__global__ __launch_bounds__(1024) void k_scan(const int* __restrict__ cnt16,
                                               const int* __restrict__ dcnt,
                                               int* __restrict__ off,
                                               int* __restrict__ doff,
                                               int* __restrict__ cursor16,
                                               int* __restrict__ dcursor) {
    __shared__ int s[1024];
    const int t = threadIdx.x;
    if (blockIdx.x == 0) {
        const int v = (t < R2) ? cnt16[t * 16] : 0;
        s[t] = v;
        __syncthreads();
        for (int d = 1; d < 1024; d <<= 1) {
            const int p = (t >= d) ? s[t - d] : 0;
            __syncthreads();
            s[t] += p;
            __syncthreads();
        }
        if (t == 0) off[0] = 0;
        if (t < R2) {
            off[t + 1] = s[t];
            cursor16[t * 16] = s[t] - v;         // exclusive offset
        }
    } else {
        const int base = t * 8;
        int loc[8];
        int run = 0;
#pragma unroll
        for (int q = 0; q < 8; ++q) {
            const int v = (base + q < N_NODES) ? dcnt[base + q] : 0;
            loc[q] = run;
            run += v;
        }
        s[t] = run;
        __syncthreads();
        for (int d = 1; d < 1024; d <<= 1) {
            const int p = (t >= d) ? s[t - d] : 0;
            __syncthreads();
            s[t] += p;
            __syncthreads();
        }
        const int ex = s[t] - run;
#pragma unroll
        for (int q = 0; q < 8; ++q) {
            if (base + q < N_NODES) {
                const int o = ex + loc[q];
                doff[base + q] = o;
                dcursor[base + q] = o;
            }
        }
        if (t == 1023) doff[N_NODES] = s[1023];
    }
}

// ---------------------------------------------------------------------------
// k_scatter: per edge, rpos = cursor by etype, dpos = cursor by dst.
// mode 0: sedge[rpos] = {src, dpos}   (primary, msg lands dst-sorted)
// mode 1: sedge[rpos] = {src, dst}    (fallback, atomic aggregation)
// ---------------------------------------------------------------------------
__global__ __launch_bounds__(256) void k_scatter(const int* __restrict__ src,
                                                 const int* __restrict__ dst,
                                                 const int* __restrict__ etype,
                                                 int* __restrict__ cursor16,
                                                 int* __restrict__ dcursor,
                                                 int2* __restrict__ sedge,
                                                 int mode) {
    const int e = blockIdx.x * 256 + threadIdx.x;
    if (e >= E_EDGES) return;
    const int r = etype[e];
    const int d = dst[e];
    const int rpos = atomicAdd(&cursor16[r * 16], 1);
    int y;
    if (mode == 0) y = atomicAdd(&dcursor[d], 1);   // dpos
    else           y = d;
    sedge[rpos] = make_int2(src[e], y);
}

// ---------------------------------------------------------------------------
// k_edge (primary): relation-binned messages -> bf16 store at dst-sorted slot.
// XCD-banded; W[r] column in registers; 2-edge ILP scalar-load pipeline.
// ---------------------------------------------------------------------------
__global__ __launch_bounds__(256) void k_edge(const float* __restrict__ feat,
                                              const unsigned short* __restrict__ relWh,
                                              const int2* __restrict__ sedge,
                                              const int* __restrict__ off,
                                              unsigned short* __restrict__ msg) {
    const int xcd = blockIdx.x & 7;
    const int j = blockIdx.x >> 3;           // [0,200)
    const int r = xcd * 50 + (j >> 2);       // CPR=4
    const int chunk = j & 3;
    const int lane = threadIdx.x & 63;
    const int wv = threadIdx.x >> 6;
    const int beg = off[r];
    const int cnt = off[r + 1] - beg;
    const int cbeg = beg + (cnt * chunk) / CPR;
    const int cend = beg + (cnt * (chunk + 1)) / CPR;

    const unsigned short* __restrict__ Wh = relWh + r * 4096;
    float w[64];
#pragma unroll
    for (int i = 0; i < 64; ++i) w[i] = bf2f(Wh[i * 64 + lane]);

    int idx = cbeg + wv;
    for (; idx + 4 < cend; idx += 8) {
        const int iB = idx + 4;
        const int2 eA = sedge[idx];
        const int2 eB = sedge[iB];
        const int sA = __builtin_amdgcn_readfirstlane(eA.x);
        const int dA = __builtin_amdgcn_readfirstlane(eA.y);
        const int sB = __builtin_amdgcn_readfirstlane(eB.x);
        const int dB = __builtin_amdgcn_readfirstlane(eB.y);
        const float* __restrict__ fA = feat + sA * 64;   // uniform -> s_load
        const float* __restrict__ fB = feat + sB * 64;
        float a0 = 0.f, a1 = 0.f, a2 = 0.f, a3 = 0.f;
        float b0 = 0.f, b1 = 0.f, b2 = 0.f, b3 = 0.f;
#pragma unroll
        for (int i = 0; i < 64; i += 4) {
            a0 = fmaf(fA[i    ], w[i    ], a0);  b0 = fmaf(fB[i    ], w[i    ], b0);
            a1 = fmaf(fA[i + 1], w[i + 1], a1);  b1 = fmaf(fB[i + 1], w[i + 1], b1);
            a2 = fmaf(fA[i + 2], w[i + 2], a2);  b2 = fmaf(fB[i + 2], w[i + 2], b2);
            a3 = fmaf(fA[i + 3], w[i + 3], a3);  b3 = fmaf(fB[i + 3], w[i + 3], b3);
        }
        msg[dA * 64 + lane] = f2bf((a0 + a1) + (a2 + a3));  // one 128B line
        msg[dB * 64 + lane] = f2bf((b0 + b1) + (b2 + b3));
    }
    for (; idx < cend; idx += 4) {
        const int2 eA = sedge[idx];
        const int sA = __builtin_amdgcn_readfirstlane(eA.x);
        const int dA = __builtin_amdgcn_readfirstlane(eA.y);
        const float* __restrict__ frow = feat + sA * 64;
        float a0 = 0.f, a1 = 0.f, a2 = 0.f, a3 = 0.f;
#pragma unroll
        for (int i = 0; i < 64; i += 4) {
            a0 = fmaf(frow[i    ], w[i    ], a0);
            a1 = fmaf(frow[i + 1], w[i + 1], a1);
            a2 = fmaf(frow[i + 2], w[i + 2], a2);
            a3 = fmaf(frow[i + 3], w[i + 3], a3);
        }
        msg[dA * 64 + lane] = f2bf((a0 + a1) + (a2 + a3));
    }
}

// ---------------------------------------------------------------------------
// k_edge_at (fallback): atomic aggregation, sedge = {src, dst}.
// ---------------------------------------------------------------------------
__global__ __launch_bounds__(256) void k_edge_at(const float* __restrict__ feat,
                                                 const unsigned short* __restrict__ relWh,
                                                 const int2* __restrict__ sedge,
                                                 const int* __restrict__ off,
                                                 float* __restrict__ nei_sum) {
    const int xcd = blockIdx.x & 7;
    const int j = blockIdx.x >> 3;
    const int r = xcd * 50 + (j >> 2);
    const int chunk = j & 3;
    const int lane = threadIdx.x & 63;
    const int wv = threadIdx.x >> 6;
    const int beg = off[r];
    const int cnt = off[r + 1] - beg;
    const int cbeg = beg + (cnt * chunk) / CPR;
    const int cend = beg + (cnt * (chunk + 1)) / CPR;

    const unsigned short* __restrict__ Wh = relWh + r * 4096;
    float w[64];
#pragma unroll
    for (int i = 0; i < 64; ++i) w[i] = bf2f(Wh[i * 64 + lane]);

    for (int idx = cbeg + wv; idx < cend; idx += 4) {
        const int2 eA = sedge[idx];
        const int s = __builtin_amdgcn_readfirstlane(eA.x);
        const int d = __builtin_amdgcn_readfirstlane(eA.y);
        const float* __restrict__ frow = feat + s * 64;
        float a0 = 0.f, a1 = 0.f, a2 = 0.f, a3 = 0.f;
#pragma unroll
        for (int i = 0; i < 64; i += 4) {
            a0 = fmaf(frow[i    ], w[i    ], a0);
            a1 = fmaf(frow[i + 1], w[i + 1], a1);
            a2 = fmaf(frow[i + 2], w[i + 2], a2);
            a3 = fmaf(frow[i + 3], w[i + 3], a3);
        }
        atomicAdd(&nei_sum[d * 64 + lane], (a0 + a1) + (a2 + a3));
    }
}

// ---------------------------------------------------------------------------
// k_post (primary): blocks [0,500)   -> node epilogue, CONTIGUOUS mailbox sum
//                   blocks [500,600) -> rel_emb @ W_R^T + b
// ---------------------------------------------------------------------------
__global__ __launch_bounds__(256) void k_post(const float* __restrict__ feat,
                                              const float* __restrict__ slw,
                                              const int* __restrict__ doff,
                                              const unsigned short* __restrict__ msg,
                                              const float* __restrict__ rel_emb,
                                              const float* __restrict__ Wr,
                                              const float* __restrict__ br,
                                              float* __restrict__ out) {
    __shared__ float s_w[4096];
    const int blk = blockIdx.x;
    const int t = threadIdx.x;
    const int lane = t & 63;
    const int wv = t >> 6;
    if (blk < 500) {
#pragma unroll
        for (int k = 0; k < 16; ++k) s_w[k * 256 + t] = slw[k * 256 + t];
        __syncthreads();
#pragma unroll
        for (int q = 0; q < 4; ++q) {
            const int n = blk * 16 + wv * 4 + q;
            const int b0 = doff[n];
            const int b1 = doff[n + 1];
            const float* __restrict__ frow = feat + n * 64;   // uniform -> s_load
            const float fa = frow[lane];
            float acc = 0.f;
#pragma unroll
            for (int i = 0; i < 64; ++i)
                acc = fmaf(frow[i], s_w[i * 64 + lane], acc);  // 2-way alias: free
            float sm = 0.f;
            int jj = b0;
            for (; jj + 1 < b1; jj += 2) {                     // streaming rows
                const float m0 = bf2f(msg[jj * 64 + lane]);
                const float m1 = bf2f(msg[(jj + 1) * 64 + lane]);
                sm += m0 + m1;
            }
            if (jj < b1) sm += bf2f(msg[jj * 64 + lane]);
            const float inv = 1.0f / fmaxf((float)(b1 - b0), 1.0f);
            out[n * 128 + lane] = fa;
            out[n * 128 + 64 + lane] = fmaf(sm, inv, acc);
        }
    } else {
        // s_w[k*64+j] = Wr[j*64+k]
#pragma unroll
        for (int k = 0; k < 16; ++k) {
            const int idx = k * 256 + t;
            s_w[(idx & 63) * 64 + (idx >> 6)] = Wr[idx];
        }
        __syncthreads();
        const int r = (blk - 500) * 4 + wv;
        const float re = rel_emb[r * 64 + lane];
        float acc = br[lane];
#pragma unroll
        for (int k = 0; k < 64; ++k)
            acc = fmaf(bcast(re, k), s_w[k * 64 + lane], acc);
        out[N_NODES * 128 + r * 64 + lane] = acc;
    }
}

// ---------------------------------------------------------------------------
// k_post_at (fallback): reads nei_sum, degree from doff deltas.
// ---------------------------------------------------------------------------
__global__ __launch_bounds__(256) void k_post_at(const float* __restrict__ feat,
                                                 const float* __restrict__ slw,
                                                 const float* __restrict__ nei_sum,
                                                 const int* __restrict__ doff,
                                                 const float* __restrict__ rel_emb,
                                                 const float* __restrict__ Wr,
                                                 const float* __restrict__ br,
                                                 float* __restrict__ out) {
    __shared__ float s_w[4096];
    const int blk = blockIdx.x;
    const int t = threadIdx.x;
    const int lane = t & 63;
    const int wv = t >> 6;
    if (blk < 500) {
#pragma unroll
        for (int k = 0; k < 16; ++k) s_w[k * 256 + t] = slw[k * 256 + t];
        __syncthreads();
#pragma unroll
        for (int q = 0; q < 4; ++q) {
            const int n = blk * 16 + wv * 4 + q;
            const float* __restrict__ frow = feat + n * 64;
            const float fa = frow[lane];
            float acc = 0.f;
#pragma unroll
            for (int i = 0; i < 64; ++i)
                acc = fmaf(frow[i], s_w[i * 64 + lane], acc);
            const float deg = (float)(doff[n + 1] - doff[n]);
            const float inv = 1.0f / fmaxf(deg, 1.0f);
            out[n * 128 + lane] = fa;
            out[n * 128 + 64 + lane] = fmaf(nei_sum[n * 64 + lane], inv, acc);
        }
    } else {
#pragma unroll
        for (int k = 0; k < 16; ++k) {
            const int idx = k * 256 + t;
            s_w[(idx & 63) * 64 + (idx >> 6)] = Wr[idx];
        }
        __syncthreads();
        const int r = (blk - 500) * 4 + wv;
        const float re = rel_emb[r * 64 + lane];
        float acc = br[lane];
#pragma unroll
        for (int k = 0; k < 64; ++k)
            acc = fmaf(bcast(re, k), s_w[k * 64 + lane], acc);
        out[N_NODES * 128 + r * 64 + lane] = acc;
    }
}

// ---------------------------------------------------------------------------
extern "C" void kernel_launch(void* const* d_in, const int* in_sizes, int n_in,
                              void* d_out, int out_size, void* d_ws, size_t ws_size,
                              hipStream_t stream) {
    const float* feat    = (const float*)d_in[0];   // [8000,64]
    const float* rel_emb = (const float*)d_in[1];   // [400,64]
    const float* weight  = (const float*)d_in[2];   // [50,64,64]
    const float* w_comp  = (const float*)d_in[3];   // [400,50]
    const float* slw     = (const float*)d_in[4];   // [64,64]
    const float* Wr      = (const float*)d_in[5];   // [64,64]
    const float* br      = (const float*)d_in[6];   // [64]
    const int*   src     = (const int*)d_in[7];     // [128000]
    const int*   dst     = (const int*)d_in[8];     // [128000]
    const int*   etype   = (const int*)d_in[9];     // [128000]
    float* out = (float*)d_out;
    char* ws = (char*)d_ws;

    if (ws_size >= 20833728) {
        // ---- primary: dst-slotted messages, no atomics on the data path ----
        unsigned short* relWh = (unsigned short*)(ws);            //  3,276,800
        unsigned short* msg   = (unsigned short*)(ws + 3276800);  // 16,384,000
        int2* sedge   = (int2*)(ws + 19660800);                   //  1,024,000
        int* off      = (int*)(ws + 20684800);                    //      1,664
        int* doff     = (int*)(ws + 20686464);                    //     32,064
        int* cnt16    = (int*)(ws + 20718528);                    //     25,600
        int* dcnt     = (int*)(ws + 20744128);                    //     32,000
        int* cursor16 = (int*)(ws + 20776128);                    //     25,600
        int* dcursor  = (int*)(ws + 20801728);                    //     32,000

        hipMemsetAsync(cnt16, 0, 57600, stream);      // cnt16+dcnt only
        k_pre<<<600, 256, 0, stream>>>(w_comp, weight, relWh, dst, etype,
                                       cnt16, dcnt);
        k_scan<<<2, 1024, 0, stream>>>(cnt16, dcnt, off, doff, cursor16, dcursor);
        k_scatter<<<500, 256, 0, stream>>>(src, dst, etype, cursor16, dcursor,
                                           sedge, 0);
        k_edge<<<R2 * CPR, 256, 0, stream>>>(feat, relWh, sedge, off, msg);
        k_post<<<600, 256, 0, stream>>>(feat, slw, doff, msg, rel_emb, Wr, br,
                                        out);
    } else {
        // ---- compact fallback: atomic aggregation ----
        unsigned short* relWh = (unsigned short*)(ws);            //  3,276,800
        int2* sedge   = (int2*)(ws + 3276800);                    //  1,024,000
        int* off      = (int*)(ws + 4300800);                     //      1,664
        int* doff     = (int*)(ws + 4302464);                     //     32,064
        float* nei    = (float*)(ws + 4334528);                   //  2,048,000
        int* cnt16    = (int*)(ws + 6382528);                     //     25,600
        int* dcnt     = (int*)(ws + 6408128);                     //     32,000
        int* cursor16 = (int*)(ws + 6440128);                     //     25,600
        int* dcursor  = (int*)(ws + 6465728);                     //     32,000

        hipMemsetAsync(nei, 0, 2105600, stream);      // nei+cnt16+dcnt
        k_pre<<<600, 256, 0, stream>>>(w_comp, weight, relWh, dst, etype,
                                       cnt16, dcnt);
        k_scan<<<2, 1024, 0, stream>>>(cnt16, dcnt, off, doff, cursor16, dcursor);
        k_scatter<<<500, 256, 0, stream>>>(src, dst, etype, cursor16, dcursor,
                                           sedge, 1);
        k_edge_at<<<R2 * CPR, 256, 0, stream>>>(feat, relWh, sedge, off, nei);
        k_post_at<<<600, 256, 0, stream>>>(feat, slw, nei, doff, rel_emb, Wr, br,
                                           out);
    }
}

// Round 6
// 119.111 us; speedup vs baseline: 1.0466x; 1.0029x over previous
//
#include <hip/hip_runtime.h>

#define N_NODES 8000
#define E_EDGES 128000
#define NUM_BASES 50
#define R2 400
#define CPR 4      // chunks per relation in edge kernel
#define RT 16      // relation tile in relw

static __device__ __forceinline__ float bf2f(unsigned short u) {
    return __uint_as_float(((unsigned int)u) << 16);
}
static __device__ __forceinline__ unsigned short f2bf(float f) {
    unsigned int u = __float_as_uint(f);
    u += 0x7fffu + ((u >> 16) & 1u);   // round-to-nearest-even
    return (unsigned short)(u >> 16);
}
static __device__ __forceinline__ float bcast(float v, int lane) {
    return __uint_as_float(__builtin_amdgcn_readlane(__float_as_uint(v), lane));
}

// ---------------------------------------------------------------------------
// k_zero: replaces hipMemsetAsync (rocclr fill kernel costs ~41us in-graph!)
// zeroes n4 int4's at p (16B-aligned).
// ---------------------------------------------------------------------------
__global__ __launch_bounds__(256) void k_zero(int4* __restrict__ p, int n4) {
    const int i = blockIdx.x * 256 + threadIdx.x;
    if (i < n4) p[i] = make_int4(0, 0, 0, 0);
}

// ---------------------------------------------------------------------------
// k_pre: blocks [0,100)   -> rel_weight (bf16) = w_comp @ weight (tiled)
//        blocks [100,600) -> etype histogram (64B-padded) + dst histogram
// ---------------------------------------------------------------------------
__global__ __launch_bounds__(256) void k_pre(const float* __restrict__ w_comp,
                                             const float* __restrict__ weight,
                                             unsigned short* __restrict__ relWh,
                                             const int* __restrict__ dst,
                                             const int* __restrict__ etype,
                                             int* __restrict__ cnt16,
                                             int* __restrict__ dcnt) {
    const int blk = blockIdx.x;
    const int t = threadIdx.x;
    if (blk < 100) {
        const int rt = blk >> 2;                 // relation tile [0,25)
        const int pb = blk & 3;                  // position block
        const int r0 = rt * RT;
        const int p = pb * 256 + t;              // float4 index [0,1024)
        const float4* w4 = (const float4*)weight;
        float4 acc[RT];
#pragma unroll
        for (int rr = 0; rr < RT; ++rr) acc[rr] = make_float4(0.f, 0.f, 0.f, 0.f);
        for (int b = 0; b < NUM_BASES; ++b) {
            const float4 w = w4[b * 1024 + p];
#pragma unroll
            for (int rr = 0; rr < RT; ++rr) {
                const float c = w_comp[(r0 + rr) * NUM_BASES + b];
                acc[rr].x = fmaf(c, w.x, acc[rr].x);
                acc[rr].y = fmaf(c, w.y, acc[rr].y);
                acc[rr].z = fmaf(c, w.z, acc[rr].z);
                acc[rr].w = fmaf(c, w.w, acc[rr].w);
            }
        }
        ushort4* outh = (ushort4*)relWh;
#pragma unroll
        for (int rr = 0; rr < RT; ++rr) {
            ushort4 v;
            v.x = f2bf(acc[rr].x); v.y = f2bf(acc[rr].y);
            v.z = f2bf(acc[rr].z); v.w = f2bf(acc[rr].w);
            outh[(r0 + rr) * 1024 + p] = v;
        }
    } else {
        const int e = (blk - 100) * 256 + t;
        if (e >= E_EDGES) return;
        atomicAdd(&cnt16[etype[e] * 16], 1);     // one 64B line per counter
        atomicAdd(&dcnt[dst[e]], 1);
    }
}

// ---------------------------------------------------------------------------
// k_scan: block 0 -> scan 400 etype bins -> off[401], init cursor16 = off
//         block 1 -> scan 8000 dst bins  -> doff[8001], init dcursor = doff
// ---------------------------------------------------------------------------
__global__ __launch_bounds__(1024) void k_scan(const int* __restrict__ cnt16,
                                               const int* __restrict__ dcnt,
                                               int* __restrict__ off,
                                               int* __restrict__ doff,
                                               int* __restrict__ cursor16,
                                               int* __restrict__ dcursor) {
    __shared__ int s[1024];
    const int t = threadIdx.x;
    if (blockIdx.x == 0) {
        const int v = (t < R2) ? cnt16[t * 16] : 0;
        s[t] = v;
        __syncthreads();
        for (int d = 1; d < 1024; d <<= 1) {
            const int p = (t >= d) ? s[t - d] : 0;
            __syncthreads();
            s[t] += p;
            __syncthreads();
        }
        if (t == 0) off[0] = 0;
        if (t < R2) {
            off[t + 1] = s[t];
            cursor16[t * 16] = s[t] - v;         // exclusive offset
        }
    } else {
        const int base = t * 8;
        int loc[8];
        int run = 0;
#pragma unroll
        for (int q = 0; q < 8; ++q) {
            const int v = (base + q < N_NODES) ? dcnt[base + q] : 0;
            loc[q] = run;
            run += v;
        }
        s[t] = run;
        __syncthreads();
        for (int d = 1; d < 1024; d <<= 1) {
            const int p = (t >= d) ? s[t - d] : 0;
            __syncthreads();
            s[t] += p;
            __syncthreads();
        }
        const int ex = s[t] - run;
#pragma unroll
        for (int q = 0; q < 8; ++q) {
            if (base + q < N_NODES) {
                const int o = ex + loc[q];
                doff[base + q] = o;
                dcursor[base + q] = o;
            }
        }
        if (t == 1023) doff[N_NODES] = s[1023];
    }
}

// ---------------------------------------------------------------------------
// k_scatter: per edge, rpos = cursor by etype, dpos = cursor by dst.
// mode 0: sedge[rpos] = {src, dpos}   (primary, msg lands dst-sorted)
// mode 1: sedge[rpos] = {src, dst}    (fallback, atomic aggregation)
// ---------------------------------------------------------------------------
__global__ __launch_bounds__(256) void k_scatter(const int* __restrict__ src,
                                                 const int* __restrict__ dst,
                                                 const int* __restrict__ etype,
                                                 int* __restrict__ cursor16,
                                                 int* __restrict__ dcursor,
                                                 int2* __restrict__ sedge,
                                                 int mode) {
    const int e = blockIdx.x * 256 + threadIdx.x;
    if (e >= E_EDGES) return;
    const int r = etype[e];
    const int d = dst[e];
    const int rpos = atomicAdd(&cursor16[r * 16], 1);
    int y;
    if (mode == 0) y = atomicAdd(&dcursor[d], 1);   // dpos
    else           y = d;
    sedge[rpos] = make_int2(src[e], y);
}

// ---------------------------------------------------------------------------
// k_edge (primary): relation-binned messages -> bf16 store at dst-sorted slot.
// XCD-banded; W[r] column in registers; 2-edge ILP scalar-load pipeline.
// ---------------------------------------------------------------------------
__global__ __launch_bounds__(256) void k_edge(const float* __restrict__ feat,
                                              const unsigned short* __restrict__ relWh,
                                              const int2* __restrict__ sedge,
                                              const int* __restrict__ off,
                                              unsigned short* __restrict__ msg) {
    const int xcd = blockIdx.x & 7;
    const int j = blockIdx.x >> 3;           // [0,200)
    const int r = xcd * 50 + (j >> 2);       // CPR=4
    const int chunk = j & 3;
    const int lane = threadIdx.x & 63;
    const int wv = threadIdx.x >> 6;
    const int beg = off[r];
    const int cnt = off[r + 1] - beg;
    const int cbeg = beg + (cnt * chunk) / CPR;
    const int cend = beg + (cnt * (chunk + 1)) / CPR;

    const unsigned short* __restrict__ Wh = relWh + r * 4096;
    float w[64];
#pragma unroll
    for (int i = 0; i < 64; ++i) w[i] = bf2f(Wh[i * 64 + lane]);

    int idx = cbeg + wv;
    for (; idx + 4 < cend; idx += 8) {
        const int iB = idx + 4;
        const int2 eA = sedge[idx];
        const int2 eB = sedge[iB];
        const int sA = __builtin_amdgcn_readfirstlane(eA.x);
        const int dA = __builtin_amdgcn_readfirstlane(eA.y);
        const int sB = __builtin_amdgcn_readfirstlane(eB.x);
        const int dB = __builtin_amdgcn_readfirstlane(eB.y);
        const float* __restrict__ fA = feat + sA * 64;   // uniform -> s_load
        const float* __restrict__ fB = feat + sB * 64;
        float a0 = 0.f, a1 = 0.f, a2 = 0.f, a3 = 0.f;
        float b0 = 0.f, b1 = 0.f, b2 = 0.f, b3 = 0.f;
#pragma unroll
        for (int i = 0; i < 64; i += 4) {
            a0 = fmaf(fA[i    ], w[i    ], a0);  b0 = fmaf(fB[i    ], w[i    ], b0);
            a1 = fmaf(fA[i + 1], w[i + 1], a1);  b1 = fmaf(fB[i + 1], w[i + 1], b1);
            a2 = fmaf(fA[i + 2], w[i + 2], a2);  b2 = fmaf(fB[i + 2], w[i + 2], b2);
            a3 = fmaf(fA[i + 3], w[i + 3], a3);  b3 = fmaf(fB[i + 3], w[i + 3], b3);
        }
        msg[dA * 64 + lane] = f2bf((a0 + a1) + (a2 + a3));  // one 128B line
        msg[dB * 64 + lane] = f2bf((b0 + b1) + (b2 + b3));
    }
    for (; idx < cend; idx += 4) {
        const int2 eA = sedge[idx];
        const int sA = __builtin_amdgcn_readfirstlane(eA.x);
        const int dA = __builtin_amdgcn_readfirstlane(eA.y);
        const float* __restrict__ frow = feat + sA * 64;
        float a0 = 0.f, a1 = 0.f, a2 = 0.f, a3 = 0.f;
#pragma unroll
        for (int i = 0; i < 64; i += 4) {
            a0 = fmaf(frow[i    ], w[i    ], a0);
            a1 = fmaf(frow[i + 1], w[i + 1], a1);
            a2 = fmaf(frow[i + 2], w[i + 2], a2);
            a3 = fmaf(frow[i + 3], w[i + 3], a3);
        }
        msg[dA * 64 + lane] = f2bf((a0 + a1) + (a2 + a3));
    }
}

// ---------------------------------------------------------------------------
// k_edge_at (fallback): atomic aggregation, sedge = {src, dst}.
// ---------------------------------------------------------------------------
__global__ __launch_bounds__(256) void k_edge_at(const float* __restrict__ feat,
                                                 const unsigned short* __restrict__ relWh,
                                                 const int2* __restrict__ sedge,
                                                 const int* __restrict__ off,
                                                 float* __restrict__ nei_sum) {
    const int xcd = blockIdx.x & 7;
    const int j = blockIdx.x >> 3;
    const int r = xcd * 50 + (j >> 2);
    const int chunk = j & 3;
    const int lane = threadIdx.x & 63;
    const int wv = threadIdx.x >> 6;
    const int beg = off[r];
    const int cnt = off[r + 1] - beg;
    const int cbeg = beg + (cnt * chunk) / CPR;
    const int cend = beg + (cnt * (chunk + 1)) / CPR;

    const unsigned short* __restrict__ Wh = relWh + r * 4096;
    float w[64];
#pragma unroll
    for (int i = 0; i < 64; ++i) w[i] = bf2f(Wh[i * 64 + lane]);

    for (int idx = cbeg + wv; idx < cend; idx += 4) {
        const int2 eA = sedge[idx];
        const int s = __builtin_amdgcn_readfirstlane(eA.x);
        const int d = __builtin_amdgcn_readfirstlane(eA.y);
        const float* __restrict__ frow = feat + s * 64;
        float a0 = 0.f, a1 = 0.f, a2 = 0.f, a3 = 0.f;
#pragma unroll
        for (int i = 0; i < 64; i += 4) {
            a0 = fmaf(frow[i    ], w[i    ], a0);
            a1 = fmaf(frow[i + 1], w[i + 1], a1);
            a2 = fmaf(frow[i + 2], w[i + 2], a2);
            a3 = fmaf(frow[i + 3], w[i + 3], a3);
        }
        atomicAdd(&nei_sum[d * 64 + lane], (a0 + a1) + (a2 + a3));
    }
}

// ---------------------------------------------------------------------------
// k_post (primary): blocks [0,500)   -> node epilogue, CONTIGUOUS mailbox sum
//                   blocks [500,600) -> rel_emb @ W_R^T + b
// ---------------------------------------------------------------------------
__global__ __launch_bounds__(256) void k_post(const float* __restrict__ feat,
                                              const float* __restrict__ slw,
                                              const int* __restrict__ doff,
                                              const unsigned short* __restrict__ msg,
                                              const float* __restrict__ rel_emb,
                                              const float* __restrict__ Wr,
                                              const float* __restrict__ br,
                                              float* __restrict__ out) {
    __shared__ float s_w[4096];
    const int blk = blockIdx.x;
    const int t = threadIdx.x;
    const int lane = t & 63;
    const int wv = t >> 6;
    if (blk < 500) {
#pragma unroll
        for (int k = 0; k < 16; ++k) s_w[k * 256 + t] = slw[k * 256 + t];
        __syncthreads();
#pragma unroll
        for (int q = 0; q < 4; ++q) {
            const int n = blk * 16 + wv * 4 + q;
            const int b0 = doff[n];
            const int b1 = doff[n + 1];
            const float* __restrict__ frow = feat + n * 64;   // uniform -> s_load
            const float fa = frow[lane];
            float acc = 0.f;
#pragma unroll
            for (int i = 0; i < 64; ++i)
                acc = fmaf(frow[i], s_w[i * 64 + lane], acc);  // 2-way alias: free
            float sm = 0.f;
            int jj = b0;
            for (; jj + 1 < b1; jj += 2) {                     // streaming rows
                const float m0 = bf2f(msg[jj * 64 + lane]);
                const float m1 = bf2f(msg[(jj + 1) * 64 + lane]);
                sm += m0 + m1;
            }
            if (jj < b1) sm += bf2f(msg[jj * 64 + lane]);
            const float inv = 1.0f / fmaxf((float)(b1 - b0), 1.0f);
            out[n * 128 + lane] = fa;
            out[n * 128 + 64 + lane] = fmaf(sm, inv, acc);
        }
    } else {
        // s_w[k*64+j] = Wr[j*64+k]
#pragma unroll
        for (int k = 0; k < 16; ++k) {
            const int idx = k * 256 + t;
            s_w[(idx & 63) * 64 + (idx >> 6)] = Wr[idx];
        }
        __syncthreads();
        const int r = (blk - 500) * 4 + wv;
        const float re = rel_emb[r * 64 + lane];
        float acc = br[lane];
#pragma unroll
        for (int k = 0; k < 64; ++k)
            acc = fmaf(bcast(re, k), s_w[k * 64 + lane], acc);
        out[N_NODES * 128 + r * 64 + lane] = acc;
    }
}

// ---------------------------------------------------------------------------
// k_post_at (fallback): reads nei_sum, degree from doff deltas.
// ---------------------------------------------------------------------------
__global__ __launch_bounds__(256) void k_post_at(const float* __restrict__ feat,
                                                 const float* __restrict__ slw,
                                                 const float* __restrict__ nei_sum,
                                                 const int* __restrict__ doff,
                                                 const float* __restrict__ rel_emb,
                                                 const float* __restrict__ Wr,
                                                 const float* __restrict__ br,
                                                 float* __restrict__ out) {
    __shared__ float s_w[4096];
    const int blk = blockIdx.x;
    const int t = threadIdx.x;
    const int lane = t & 63;
    const int wv = t >> 6;
    if (blk < 500) {
#pragma unroll
        for (int k = 0; k < 16; ++k) s_w[k * 256 + t] = slw[k * 256 + t];
        __syncthreads();
#pragma unroll
        for (int q = 0; q < 4; ++q) {
            const int n = blk * 16 + wv * 4 + q;
            const float* __restrict__ frow = feat + n * 64;
            const float fa = frow[lane];
            float acc = 0.f;
#pragma unroll
            for (int i = 0; i < 64; ++i)
                acc = fmaf(frow[i], s_w[i * 64 + lane], acc);
            const float deg = (float)(doff[n + 1] - doff[n]);
            const float inv = 1.0f / fmaxf(deg, 1.0f);
            out[n * 128 + lane] = fa;
            out[n * 128 + 64 + lane] = fmaf(nei_sum[n * 64 + lane], inv, acc);
        }
    } else {
#pragma unroll
        for (int k = 0; k < 16; ++k) {
            const int idx = k * 256 + t;
            s_w[(idx & 63) * 64 + (idx >> 6)] = Wr[idx];
        }
        __syncthreads();
        const int r = (blk - 500) * 4 + wv;
        const float re = rel_emb[r * 64 + lane];
        float acc = br[lane];
#pragma unroll
        for (int k = 0; k < 64; ++k)
            acc = fmaf(bcast(re, k), s_w[k * 64 + lane], acc);
        out[N_NODES * 128 + r * 64 + lane] = acc;
    }
}

// ---------------------------------------------------------------------------
extern "C" void kernel_launch(void* const* d_in, const int* in_sizes, int n_in,
                              void* d_out, int out_size, void* d_ws, size_t ws_size,
                              hipStream_t stream) {
    const float* feat    = (const float*)d_in[0];   // [8000,64]
    const float* rel_emb = (const float*)d_in[1];   // [400,64]
    const float* weight  = (const float*)d_in[2];   // [50,64,64]
    const float* w_comp  = (const float*)d_in[3];   // [400,50]
    const float* slw     = (const float*)d_in[4];   // [64,64]
    const float* Wr      = (const float*)d_in[5];   // [64,64]
    const float* br      = (const float*)d_in[6];   // [64]
    const int*   src     = (const int*)d_in[7];     // [128000]
    const int*   dst     = (const int*)d_in[8];     // [128000]
    const int*   etype   = (const int*)d_in[9];     // [128000]
    float* out = (float*)d_out;
    char* ws = (char*)d_ws;

    if (ws_size >= 20833728) {
        // ---- primary: dst-slotted messages, no atomics on the data path ----
        unsigned short* relWh = (unsigned short*)(ws);            //  3,276,800
        unsigned short* msg   = (unsigned short*)(ws + 3276800);  // 16,384,000
        int2* sedge   = (int2*)(ws + 19660800);                   //  1,024,000
        int* off      = (int*)(ws + 20684800);                    //      1,664
        int* doff     = (int*)(ws + 20686464);                    //     32,064
        int* cnt16    = (int*)(ws + 20718528);                    //     25,600
        int* dcnt     = (int*)(ws + 20744128);                    //     32,000
        int* cursor16 = (int*)(ws + 20776128);                    //     25,600
        int* dcursor  = (int*)(ws + 20801728);                    //     32,000

        // zero cnt16+dcnt (57,600 B = 3600 int4) with our own kernel:
        // the rocclr fill kernel costs a flat ~41us in-graph.
        k_zero<<<15, 256, 0, stream>>>((int4*)cnt16, 3600);
        k_pre<<<600, 256, 0, stream>>>(w_comp, weight, relWh, dst, etype,
                                       cnt16, dcnt);
        k_scan<<<2, 1024, 0, stream>>>(cnt16, dcnt, off, doff, cursor16, dcursor);
        k_scatter<<<500, 256, 0, stream>>>(src, dst, etype, cursor16, dcursor,
                                           sedge, 0);
        k_edge<<<R2 * CPR, 256, 0, stream>>>(feat, relWh, sedge, off, msg);
        k_post<<<600, 256, 0, stream>>>(feat, slw, doff, msg, rel_emb, Wr, br,
                                        out);
    } else {
        // ---- compact fallback: atomic aggregation ----
        unsigned short* relWh = (unsigned short*)(ws);            //  3,276,800
        int2* sedge   = (int2*)(ws + 3276800);                    //  1,024,000
        int* off      = (int*)(ws + 4300800);                     //      1,664
        int* doff     = (int*)(ws + 4302464);                     //     32,064
        float* nei    = (float*)(ws + 4334528);                   //  2,048,000
        int* cnt16    = (int*)(ws + 6382528);                     //     25,600
        int* dcnt     = (int*)(ws + 6408128);                     //     32,000
        int* cursor16 = (int*)(ws + 6440128);                     //     25,600
        int* dcursor  = (int*)(ws + 6465728);                     //     32,000

        // zero nei..dcnt (nei 2,048,000 + cnt16 25,600 + dcnt 32,000 = 2,105,600 B
        // = 131,600 int4, contiguous)
        k_zero<<<515, 256, 0, stream>>>((int4*)nei, 131600);
        k_pre<<<600, 256, 0, stream>>>(w_comp, weight, relWh, dst, etype,
                                       cnt16, dcnt);
        k_scan<<<2, 1024, 0, stream>>>(cnt16, dcnt, off, doff, cursor16, dcursor);
        k_scatter<<<500, 256, 0, stream>>>(src, dst, etype, cursor16, dcursor,
                                           sedge, 1);
        k_edge_at<<<R2 * CPR, 256, 0, stream>>>(feat, relWh, sedge, off, nei);
        k_post_at<<<600, 256, 0, stream>>>(feat, slw, nei, doff, rel_emb, Wr, br,
                                           out);
    }
}

// Round 8
// 117.082 us; speedup vs baseline: 1.0647x; 1.0173x over previous
//
#include <hip/hip_runtime.h>

#define N_NODES 8000
#define E_EDGES 128000
#define NUM_BASES 50
#define R2 400
#define CPR 8      // chunks per relation in edge kernel (1 wave each)
#define RT 16      // relation tile in relw
#define HB 32      // histogram/scatter blocks
#define EPB (E_EDGES / HB)   // 4000 edges per hist/scatter block

static __device__ __forceinline__ float bf2f(unsigned short u) {
    return __uint_as_float(((unsigned int)u) << 16);
}
static __device__ __forceinline__ unsigned short f2bf(float f) {
    unsigned int u = __float_as_uint(f);
    u += 0x7fffu + ((u >> 16) & 1u);   // round-to-nearest-even
    return (unsigned short)(u >> 16);
}
static __device__ __forceinline__ float bcast(float v, int lane) {
    return __uint_as_float(__builtin_amdgcn_readlane(__float_as_uint(v), lane));
}

// ---------------------------------------------------------------------------
// k_zero: zero n4 int4's (used for padded dst counters; rocclr fill is slow)
// ---------------------------------------------------------------------------
__global__ __launch_bounds__(256) void k_zero(int4* __restrict__ p, int n4) {
    const int i = blockIdx.x * 256 + threadIdx.x;
    if (i < n4) p[i] = make_int4(0, 0, 0, 0);
}

// ---------------------------------------------------------------------------
// k_pre: blocks [0,100)   -> rel_weight (bf16) = w_comp @ weight (tiled)
//        blocks [100,132) -> per-block LDS etype histogram -> bcnt (plain
//                            stores, NO global atomics) + padded dst histogram
// ---------------------------------------------------------------------------
__global__ __launch_bounds__(256) void k_pre(const float* __restrict__ w_comp,
                                             const float* __restrict__ weight,
                                             unsigned short* __restrict__ relWh,
                                             const int* __restrict__ dst,
                                             const int* __restrict__ etype,
                                             int* __restrict__ bcnt,
                                             int* __restrict__ dcnt16) {
    const int blk = blockIdx.x;
    const int t = threadIdx.x;
    if (blk < 100) {
        const int rt = blk >> 2;                 // relation tile [0,25)
        const int pb = blk & 3;                  // position block
        const int r0 = rt * RT;
        const int p = pb * 256 + t;              // float4 index [0,1024)
        const float4* w4 = (const float4*)weight;
        float4 acc[RT];
#pragma unroll
        for (int rr = 0; rr < RT; ++rr) acc[rr] = make_float4(0.f, 0.f, 0.f, 0.f);
        for (int b = 0; b < NUM_BASES; ++b) {
            const float4 w = w4[b * 1024 + p];
#pragma unroll
            for (int rr = 0; rr < RT; ++rr) {
                const float c = w_comp[(r0 + rr) * NUM_BASES + b];
                acc[rr].x = fmaf(c, w.x, acc[rr].x);
                acc[rr].y = fmaf(c, w.y, acc[rr].y);
                acc[rr].z = fmaf(c, w.z, acc[rr].z);
                acc[rr].w = fmaf(c, w.w, acc[rr].w);
            }
        }
        ushort4* outh = (ushort4*)relWh;
#pragma unroll
        for (int rr = 0; rr < RT; ++rr) {
            ushort4 v;
            v.x = f2bf(acc[rr].x); v.y = f2bf(acc[rr].y);
            v.z = f2bf(acc[rr].z); v.w = f2bf(acc[rr].w);
            outh[(r0 + rr) * 1024 + p] = v;
        }
    } else {
        __shared__ int lcnt[R2];
        const int hb = blk - 100;                // [0,32)
        for (int i = t; i < R2; i += 256) lcnt[i] = 0;
        __syncthreads();
        const int e0 = hb * EPB;
        for (int e = e0 + t; e < e0 + EPB; e += 256) {
            atomicAdd(&lcnt[etype[e]], 1);               // LDS atomic, cheap
            atomicAdd(&dcnt16[dst[e] * 16], 1);          // one 64B line each
        }
        __syncthreads();
        for (int i = t; i < R2; i += 256) bcnt[hb * R2 + i] = lcnt[i];
    }
}

// ---------------------------------------------------------------------------
// k_scan: block 0 (512 thr) -> etype: tot[r] = sum_b bcnt[b][r]; shfl-scan ->
//                              off[401]; bbase[b][r] = off[r] + prefix_b
//         block 1 (512 thr, 256 active) -> dst: shfl-scan of 8000 padded
//                              counters -> doff[8001], dcursor16 = doff
// BOUNDS: base+q MUST be guarded vs N_NODES (unguarded R7 version overwrote
// bcnt and read poison -> wrong bbase -> wrong relation bins).
// ---------------------------------------------------------------------------
__global__ __launch_bounds__(512) void k_scan(const int* __restrict__ bcnt,
                                              const int* __restrict__ dcnt16,
                                              int* __restrict__ off,
                                              int* __restrict__ doff,
                                              int* __restrict__ bbase,
                                              int* __restrict__ dcursor16) {
    __shared__ int sh[8];
    const int t = threadIdx.x;
    const int lane = t & 63;
    const int wid = t >> 6;
    if (blockIdx.x == 0) {
        int tot = 0;
        if (t < R2)
            for (int b = 0; b < HB; ++b) tot += bcnt[b * R2 + t];
        // inclusive shfl-scan over 512 threads
        int v = tot;
#pragma unroll
        for (int d = 1; d < 64; d <<= 1) {
            const int u = __shfl_up(v, d, 64);
            if (lane >= d) v += u;
        }
        if (lane == 63) sh[wid] = v;
        __syncthreads();
        int wo = 0;
        for (int i = 0; i < wid; ++i) wo += sh[i];
        const int incl = v + wo;
        const int ex = incl - tot;
        if (t == 0) off[0] = 0;
        if (t < R2) {
            off[t + 1] = incl;
            int run = ex;
            for (int b = 0; b < HB; ++b) {
                bbase[b * R2 + t] = run;
                run += bcnt[b * R2 + t];
            }
        }
    } else {
        int loc[32];
        int run = 0;
        const int base = t * 32;
        if (t < 256) {
#pragma unroll
            for (int q = 0; q < 32; ++q) {
                const int v = (base + q < N_NODES) ? dcnt16[(base + q) * 16] : 0;
                loc[q] = run;
                run += v;
            }
        }
        int v = (t < 256) ? run : 0;
#pragma unroll
        for (int d = 1; d < 64; d <<= 1) {
            const int u = __shfl_up(v, d, 64);
            if (lane >= d) v += u;
        }
        if (lane == 63 && wid < 4) sh[wid] = v;
        __syncthreads();
        if (t < 256) {
            int wo = 0;
            for (int i = 0; i < wid; ++i) wo += sh[i];
            const int incl = v + wo;
            const int ex = incl - run;
#pragma unroll
            for (int q = 0; q < 32; ++q) {
                if (base + q < N_NODES) {
                    const int o = ex + loc[q];
                    doff[base + q] = o;
                    dcursor16[(base + q) * 16] = o;
                }
            }
            if (t == 255) doff[N_NODES] = incl;   // runs past 8000 are 0
        }
    }
}

// ---------------------------------------------------------------------------
// k_scatter: same 32-block partition as hist. rpos via LDS cursor seeded from
// bbase (NO global atomics for etype); dpos via padded global cursor.
// sedge[rpos] = {src, dpos} -> msg lands dst-sorted.
// ---------------------------------------------------------------------------
__global__ __launch_bounds__(256) void k_scatter(const int* __restrict__ src,
                                                 const int* __restrict__ dst,
                                                 const int* __restrict__ etype,
                                                 const int* __restrict__ bbase,
                                                 int* __restrict__ dcursor16,
                                                 int2* __restrict__ sedge) {
    __shared__ int lcur[R2];
    const int blk = blockIdx.x;          // [0,32)
    const int t = threadIdx.x;
    for (int i = t; i < R2; i += 256) lcur[i] = bbase[blk * R2 + i];
    __syncthreads();
    const int e0 = blk * EPB;
    for (int e = e0 + t; e < e0 + EPB; e += 256) {
        const int r = etype[e];
        const int d = dst[e];
        const int rpos = atomicAdd(&lcur[r], 1);            // LDS atomic
        const int dpos = atomicAdd(&dcursor16[d * 16], 1);  // padded line
        sedge[rpos] = make_int2(src[e], dpos);
    }
}

// ---------------------------------------------------------------------------
// k_edge: ONE WAVE per block, __launch_bounds__(64,1) so W[r] column (64
// floats) genuinely stays in VGPRs (256-thread version spilled to L1 reloads:
// VGPR_Count was 40). XCD-banded relations; scalarized feat rows; ILP-2.
// ---------------------------------------------------------------------------
__global__ __launch_bounds__(64, 1) void k_edge(const float* __restrict__ feat,
                                                const unsigned short* __restrict__ relWh,
                                                const int2* __restrict__ sedge,
                                                const int* __restrict__ off,
                                                unsigned short* __restrict__ msg) {
    const int blk = blockIdx.x;              // [0, 3200)
    const int xcd = blk & 7;
    const int j = blk >> 3;                  // [0,400)
    const int r = xcd * 50 + (j >> 3);       // CPR=8
    const int chunk = j & 7;
    const int lane = threadIdx.x;
    const int beg = off[r];
    const int cnt = off[r + 1] - beg;
    const int cbeg = beg + (cnt * chunk) / CPR;
    const int cend = beg + (cnt * (chunk + 1)) / CPR;

    const unsigned short* __restrict__ Wh = relWh + r * 4096;
    float w[64];
#pragma unroll
    for (int i = 0; i < 64; ++i) w[i] = bf2f(Wh[i * 64 + lane]);

    int idx = cbeg;
    for (; idx + 1 < cend; idx += 2) {
        const int2 eA = sedge[idx];
        const int2 eB = sedge[idx + 1];
        const int sA = __builtin_amdgcn_readfirstlane(eA.x);
        const int dA = __builtin_amdgcn_readfirstlane(eA.y);
        const int sB = __builtin_amdgcn_readfirstlane(eB.x);
        const int dB = __builtin_amdgcn_readfirstlane(eB.y);
        const float* __restrict__ fA = feat + sA * 64;   // uniform -> s_load
        const float* __restrict__ fB = feat + sB * 64;
        float a0 = 0.f, a1 = 0.f, a2 = 0.f, a3 = 0.f;
        float b0 = 0.f, b1 = 0.f, b2 = 0.f, b3 = 0.f;
#pragma unroll
        for (int i = 0; i < 64; i += 4) {
            a0 = fmaf(fA[i    ], w[i    ], a0);  b0 = fmaf(fB[i    ], w[i    ], b0);
            a1 = fmaf(fA[i + 1], w[i + 1], a1);  b1 = fmaf(fB[i + 1], w[i + 1], b1);
            a2 = fmaf(fA[i + 2], w[i + 2], a2);  b2 = fmaf(fB[i + 2], w[i + 2], b2);
            a3 = fmaf(fA[i + 3], w[i + 3], a3);  b3 = fmaf(fB[i + 3], w[i + 3], b3);
        }
        msg[dA * 64 + lane] = f2bf((a0 + a1) + (a2 + a3));  // one 128B line
        msg[dB * 64 + lane] = f2bf((b0 + b1) + (b2 + b3));
    }
    if (idx < cend) {
        const int2 eA = sedge[idx];
        const int sA = __builtin_amdgcn_readfirstlane(eA.x);
        const int dA = __builtin_amdgcn_readfirstlane(eA.y);
        const float* __restrict__ frow = feat + sA * 64;
        float a0 = 0.f, a1 = 0.f, a2 = 0.f, a3 = 0.f;
#pragma unroll
        for (int i = 0; i < 64; i += 4) {
            a0 = fmaf(frow[i    ], w[i    ], a0);
            a1 = fmaf(frow[i + 1], w[i + 1], a1);
            a2 = fmaf(frow[i + 2], w[i + 2], a2);
            a3 = fmaf(frow[i + 3], w[i + 3], a3);
        }
        msg[dA * 64 + lane] = f2bf((a0 + a1) + (a2 + a3));
    }
}

// ---------------------------------------------------------------------------
// k_post: blocks [0,500)   -> node epilogue, CONTIGUOUS mailbox sum (ILP-4)
//         blocks [500,600) -> rel_emb @ W_R^T + b
// ---------------------------------------------------------------------------
__global__ __launch_bounds__(256) void k_post(const float* __restrict__ feat,
                                              const float* __restrict__ slw,
                                              const int* __restrict__ doff,
                                              const unsigned short* __restrict__ msg,
                                              const float* __restrict__ rel_emb,
                                              const float* __restrict__ Wr,
                                              const float* __restrict__ br,
                                              float* __restrict__ out) {
    __shared__ float s_w[4096];
    const int blk = blockIdx.x;
    const int t = threadIdx.x;
    const int lane = t & 63;
    const int wv = t >> 6;
    if (blk < 500) {
#pragma unroll
        for (int k = 0; k < 16; ++k) s_w[k * 256 + t] = slw[k * 256 + t];
        __syncthreads();
#pragma unroll
        for (int q = 0; q < 4; ++q) {
            const int n = blk * 16 + wv * 4 + q;
            const int b0 = doff[n];
            const int b1 = doff[n + 1];
            const float* __restrict__ frow = feat + n * 64;   // uniform -> s_load
            const float fa = frow[lane];
            float acc = 0.f;
#pragma unroll
            for (int i = 0; i < 64; ++i)
                acc = fmaf(frow[i], s_w[i * 64 + lane], acc);  // 2-way alias: free
            float sm = 0.f;
            int jj = b0;
            for (; jj + 3 < b1; jj += 4) {                     // streaming, ILP-4
                const float m0 = bf2f(msg[jj * 64 + lane]);
                const float m1 = bf2f(msg[(jj + 1) * 64 + lane]);
                const float m2 = bf2f(msg[(jj + 2) * 64 + lane]);
                const float m3 = bf2f(msg[(jj + 3) * 64 + lane]);
                sm += (m0 + m1) + (m2 + m3);
            }
            for (; jj < b1; ++jj) sm += bf2f(msg[jj * 64 + lane]);
            const float inv = 1.0f / fmaxf((float)(b1 - b0), 1.0f);
            out[n * 128 + lane] = fa;
            out[n * 128 + 64 + lane] = fmaf(sm, inv, acc);
        }
    } else {
        // s_w[k*64+j] = Wr[j*64+k]
#pragma unroll
        for (int k = 0; k < 16; ++k) {
            const int idx = k * 256 + t;
            s_w[(idx & 63) * 64 + (idx >> 6)] = Wr[idx];
        }
        __syncthreads();
        const int r = (blk - 500) * 4 + wv;
        const float re = rel_emb[r * 64 + lane];
        float acc = br[lane];
#pragma unroll
        for (int k = 0; k < 64; ++k)
            acc = fmaf(bcast(re, k), s_w[k * 64 + lane], acc);
        out[N_NODES * 128 + r * 64 + lane] = acc;
    }
}

// ---------------------------------------------------------------------------
extern "C" void kernel_launch(void* const* d_in, const int* in_sizes, int n_in,
                              void* d_out, int out_size, void* d_ws, size_t ws_size,
                              hipStream_t stream) {
    const float* feat    = (const float*)d_in[0];   // [8000,64]
    const float* rel_emb = (const float*)d_in[1];   // [400,64]
    const float* weight  = (const float*)d_in[2];   // [50,64,64]
    const float* w_comp  = (const float*)d_in[3];   // [400,50]
    const float* slw     = (const float*)d_in[4];   // [64,64]
    const float* Wr      = (const float*)d_in[5];   // [64,64]
    const float* br      = (const float*)d_in[6];   // [64]
    const int*   src     = (const int*)d_in[7];     // [128000]
    const int*   dst     = (const int*)d_in[8];     // [128000]
    const int*   etype   = (const int*)d_in[9];     // [128000]
    float* out = (float*)d_out;
    char* ws = (char*)d_ws;

    unsigned short* relWh   = (unsigned short*)(ws);            //  3,276,800
    unsigned short* msg     = (unsigned short*)(ws + 3276800);  // 16,384,000
    int2* sedge     = (int2*)(ws + 19660800);                   //  1,024,000
    int* off        = (int*)(ws + 20684800);                    //      1,664
    int* doff       = (int*)(ws + 20686464);                    //     32,064
    int* bcnt       = (int*)(ws + 20718528);                    //     51,200
    int* bbase      = (int*)(ws + 20769728);                    //     51,200
    int* dcnt16     = (int*)(ws + 20820928);                    //    512,000
    int* dcursor16  = (int*)(ws + 21332928);                    //    512,000

    // zero only the padded dst histogram (512,000 B = 32,000 int4)
    k_zero<<<125, 256, 0, stream>>>((int4*)dcnt16, 32000);
    k_pre<<<132, 256, 0, stream>>>(w_comp, weight, relWh, dst, etype,
                                   bcnt, dcnt16);
    k_scan<<<2, 512, 0, stream>>>(bcnt, dcnt16, off, doff, bbase, dcursor16);
    k_scatter<<<HB, 256, 0, stream>>>(src, dst, etype, bbase, dcursor16, sedge);
    k_edge<<<R2 * CPR, 64, 0, stream>>>(feat, relWh, sedge, off, msg);
    k_post<<<600, 256, 0, stream>>>(feat, slw, doff, msg, rel_emb, Wr, br, out);
}